// Round 1
// baseline (194.073 us; speedup 1.0000x reference)
//
#include <hip/hip_runtime.h>
#include <math.h>

// DTW loss: B=64 batches, N=512 timesteps, D=2 features, L1 point cost.
// D[i][j] = C[i][j] + min(D[i-1][j], D[i-1][j-1], D[i][j-1]);
// D[0][:] = cumsum(C[0][:]);  answer = mean_b D[N-1][N-1].
//
// Round-1 strategy: anti-diagonal wavefront, one 512-thread block per batch.
// Thread j owns column j; 3 rotating LDS diagonal buffers; 1 barrier/diagonal.

constexpr int NSEQ  = 512;
constexpr int BATCH = 64;

__global__ __launch_bounds__(512) void dtw_wavefront(
    const float* __restrict__ pred,    // (B, N, 2)
    const float* __restrict__ target,  // (B, N, 2)
    float* __restrict__ per_batch)     // (B,)
{
    const int b = blockIdx.x;
    const int j = threadIdx.x;

    __shared__ float xs0[NSEQ];
    __shared__ float xs1[NSEQ];
    __shared__ float buf[3][NSEQ];   // rotating anti-diagonal buffers

    // Stage x = pred[b] into LDS; y_j lives in registers of thread j.
    const float2 xv = reinterpret_cast<const float2*>(pred)[b * NSEQ + j];
    xs0[j] = xv.x;
    xs1[j] = xv.y;
    const float2 yv = reinterpret_cast<const float2*>(target)[b * NSEQ + j];
    const float y0 = yv.x, y1 = yv.y;
    __syncthreads();

    const float INF = INFINITY;
    float last = 0.f;

    // Diagonal k holds cells (i, j) with i + j == k.
    // Cell (i,j) needs:
    //   up   = D[i-1][j]   -> diag k-1, thread j
    //   left = D[i][j-1]   -> diag k-1, thread j-1
    //   diag = D[i-1][j-1] -> diag k-2, thread j-1
    // Write diag k into buf[k%3]; read k-1 from buf[(k+2)%3], k-2 from buf[(k+1)%3].
    // Writes touch the buffer holding diag k-3 (dead), so ONE barrier per step
    // both publishes this step's writes and protects next step's overwrites.
    for (int k = 0; k < 2 * NSEQ - 1; ++k) {
        const int i = k - j;
        float* cur       = buf[k % 3];
        const float* p1  = buf[(k + 2) % 3];
        const float* p2  = buf[(k + 1) % 3];
        if (i >= 0 && i < NSEQ) {
            const float c = fabsf(xs0[i] - y0) + fabsf(xs1[i] - y1);
            float up   = (i >= 1)            ? p1[j]     : INF;
            float left = (j >= 1)            ? p1[j - 1] : INF;
            float dg   = (i >= 1 && j >= 1)  ? p2[j - 1] : INF;
            float m = fminf(fminf(up, dg), left);
            if (k == 0) m = 0.f;             // D[0][0] = C[0][0]
            const float v = c + m;
            cur[j] = v;
            last = v;                         // thread N-1's final write is D[N-1][N-1]
        }
        __syncthreads();
    }

    if (j == NSEQ - 1) per_batch[b] = last;
}

__global__ void dtw_reduce(const float* __restrict__ per_batch,
                           float* __restrict__ out)
{
    // One wave of 64 lanes == BATCH
    float v = per_batch[threadIdx.x];
#pragma unroll
    for (int off = 32; off >= 1; off >>= 1)
        v += __shfl_down(v, off);
    if (threadIdx.x == 0)
        out[0] = v * (1.0f / BATCH);
}

extern "C" void kernel_launch(void* const* d_in, const int* in_sizes, int n_in,
                              void* d_out, int out_size, void* d_ws, size_t ws_size,
                              hipStream_t stream) {
    const float* pred   = (const float*)d_in[0];
    const float* target = (const float*)d_in[1];
    float* out = (float*)d_out;
    float* per_batch = (float*)d_ws;   // BATCH floats of scratch

    dtw_wavefront<<<BATCH, NSEQ, 0, stream>>>(pred, target, per_batch);
    dtw_reduce<<<1, 64, 0, stream>>>(per_batch, out);
}

// Round 2
// 72.377 us; speedup vs baseline: 2.6814x; 2.6814x over previous
//
#include <hip/hip_runtime.h>
#include <math.h>

// DTW loss: B=64, N=512, D=2, L1 cost.
// Round-2: one wave64 per batch; lane j owns columns [8j, 8j+8).
// Anti-diagonal over strips: at step k lane j computes row i = k - j across
// its 8 columns (serial chain in registers). Only cross-lane value is the
// strip boundary D[i][8j-1] = lane (j-1)'s prev[7] from step k-1 -> one
// __shfl_up per step. Zero barriers in the DP loop.

constexpr int NSEQ  = 512;
constexpr int BATCH = 64;
constexpr int P     = 8;    // columns per lane
constexpr int LANES = 64;   // one wave

__global__ __launch_bounds__(LANES) void dtw_strip(
    const float* __restrict__ pred,    // (B, N, 2)  -> rows i (x)
    const float* __restrict__ target,  // (B, N, 2)  -> cols j (y)
    float* __restrict__ per_batch)     // (B,)
{
    const int b = blockIdx.x;
    const int j = threadIdx.x;   // lane within the single wave

    __shared__ float2 xs[NSEQ];  // pred[b] staged; ds_read_b64 per step

#pragma unroll
    for (int t = 0; t < NSEQ / LANES; ++t) {
        const int idx = t * LANES + j;
        xs[idx] = reinterpret_cast<const float2*>(pred)[b * NSEQ + idx];
    }

    // y values for my 8 columns live in registers
    float Y0[P], Y1[P];
#pragma unroll
    for (int c = 0; c < P; ++c) {
        const float2 yv = reinterpret_cast<const float2*>(target)[b * NSEQ + j * P + c];
        Y0[c] = yv.x; Y1[c] = yv.y;
    }
    __syncthreads();   // publish xs (only barrier in the kernel)

    const float INF = INFINITY;
    float prev[P];     // D[i-1][my cols]
#pragma unroll
    for (int c = 0; c < P; ++c) prev[c] = INF;
    float dg0 = INF;   // D[i-1][8j-1]

    // ---- Phase A: k = 0..63 (ramp; i may be <0 or ==0) ----
    for (int k = 0; k < LANES; ++k) {
        float left_in = __shfl_up(prev[P-1], 1);   // D[i][8j-1]
        if (j == 0) left_in = (k == 0) ? 0.0f : INF;
        const int i = k - j;
        if (i >= 0) {
            const float2 x = xs[i];
            float v[P];
            if (i == 0) {
                // row 0: cumsum of costs (up = dg = INF)
                v[0] = fabsf(x.x - Y0[0]) + fabsf(x.y - Y1[0]) + left_in;
#pragma unroll
                for (int c = 1; c < P; ++c)
                    v[c] = fabsf(x.x - Y0[c]) + fabsf(x.y - Y1[c]) + v[c-1];
            } else {
                v[0] = fabsf(x.x - Y0[0]) + fabsf(x.y - Y1[0])
                     + fminf(fminf(prev[0], dg0), left_in);
#pragma unroll
                for (int c = 1; c < P; ++c)
                    v[c] = fabsf(x.x - Y0[c]) + fabsf(x.y - Y1[c])
                         + fminf(fminf(prev[c], prev[c-1]), v[c-1]);
            }
#pragma unroll
            for (int c = 0; c < P; ++c) prev[c] = v[c];
        }
        dg0 = left_in;   // D[i][8j-1] becomes next step's diag
    }

    // ---- Phase B: k = 64..511 (steady: all lanes active, i >= 1) ----
#pragma unroll 2
    for (int k = LANES; k < NSEQ; ++k) {
        float left_in = __shfl_up(prev[P-1], 1);
        if (j == 0) left_in = INF;
        const int i = k - j;
        const float2 x = xs[i];
        float v[P];
        v[0] = fabsf(x.x - Y0[0]) + fabsf(x.y - Y1[0])
             + fminf(fminf(prev[0], dg0), left_in);
#pragma unroll
        for (int c = 1; c < P; ++c)
            v[c] = fabsf(x.x - Y0[c]) + fabsf(x.y - Y1[c])
                 + fminf(fminf(prev[c], prev[c-1]), v[c-1]);
#pragma unroll
        for (int c = 0; c < P; ++c) prev[c] = v[c];
        dg0 = left_in;
    }

    // ---- Phase C: k = 512..574 (drain; lane j active iff j >= k-511) ----
    for (int k = NSEQ; k < NSEQ + LANES - 1; ++k) {
        float left_in = __shfl_up(prev[P-1], 1);
        const int i = k - j;
        if (i < NSEQ) {   // j==0 is always inactive here, no override needed
            const float2 x = xs[i];
            float v[P];
            v[0] = fabsf(x.x - Y0[0]) + fabsf(x.y - Y1[0])
                 + fminf(fminf(prev[0], dg0), left_in);
#pragma unroll
            for (int c = 1; c < P; ++c)
                v[c] = fabsf(x.x - Y0[c]) + fabsf(x.y - Y1[c])
                     + fminf(fminf(prev[c], prev[c-1]), v[c-1]);
#pragma unroll
            for (int c = 0; c < P; ++c) prev[c] = v[c];
            dg0 = left_in;
        }
    }

    if (j == LANES - 1) per_batch[b] = prev[P-1];   // D[N-1][N-1]
}

__global__ void dtw_reduce(const float* __restrict__ per_batch,
                           float* __restrict__ out)
{
    float v = per_batch[threadIdx.x];
#pragma unroll
    for (int off = 32; off >= 1; off >>= 1)
        v += __shfl_down(v, off);
    if (threadIdx.x == 0)
        out[0] = v * (1.0f / BATCH);
}

extern "C" void kernel_launch(void* const* d_in, const int* in_sizes, int n_in,
                              void* d_out, int out_size, void* d_ws, size_t ws_size,
                              hipStream_t stream) {
    const float* pred   = (const float*)d_in[0];
    const float* target = (const float*)d_in[1];
    float* out = (float*)d_out;
    float* per_batch = (float*)d_ws;

    dtw_strip<<<BATCH, LANES, 0, stream>>>(pred, target, per_batch);
    dtw_reduce<<<1, 64, 0, stream>>>(per_batch, out);
}

// Round 3
// 56.563 us; speedup vs baseline: 3.4311x; 1.2796x over previous
//
#include <hip/hip_runtime.h>
#include <math.h>

// DTW loss: B=64, N=512, D=2, L1 cost.
// Round-3: wave64-per-batch strip DP (lane j owns cols [8j,8j+8)), with:
//  - DPP wave_shr:1 for the strip-boundary pass (VALU, ~4cy) instead of
//    ds_bpermute (~150cy) -- the round-2 critical path was the shuffle.
//  - xs[] LDS read software-pipelined one step ahead (no lgkmcnt stall).
//  - 5-instr cell: v[c] = cost_c + min3(prev[c], prev[c-1], v[c-1]);
//    in-place prev[] update, no copies.
//  - row 0 folded into the general recurrence via INF identities
//    (prev=INF => v[c] = cost_c + v[c-1], the cumsum), no divergent branch.
//  - lane0 dg0 kept at INF always (fixes round-2 latent dg0=0 bug).

constexpr int NSEQ  = 512;
constexpr int BATCH = 64;
constexpr int P     = 8;    // columns per lane
constexpr int LANES = 64;   // one wave per batch

__device__ __forceinline__ float dpp_wshr1_inf(float v) {
    // lane i <- lane i-1's v; lane 0 <- old = +inf  (bound_ctrl=false)
    int r = __builtin_amdgcn_update_dpp(0x7F800000, __float_as_int(v),
                                        0x138, 0xF, 0xF, false);
    return __int_as_float(r);
}

__global__ __launch_bounds__(LANES) void dtw_strip(
    const float* __restrict__ pred,    // (B, N, 2) rows (x)
    const float* __restrict__ target,  // (B, N, 2) cols (y)
    float* __restrict__ per_batch)     // (B,)
{
    const int b = blockIdx.x;
    const int j = threadIdx.x;

    __shared__ float2 xs[NSEQ + 2];    // +2 pad: phase-B prefetch may touch [512]

    #pragma unroll
    for (int t = 0; t < NSEQ / LANES; ++t) {
        const int idx = t * LANES + j;
        xs[idx] = reinterpret_cast<const float2*>(pred)[b * NSEQ + idx];
    }
    float Y0[P], Y1[P];
    #pragma unroll
    for (int c = 0; c < P; ++c) {
        const float2 y = reinterpret_cast<const float2*>(target)[b * NSEQ + j * P + c];
        Y0[c] = y.x; Y1[c] = y.y;
    }
    __syncthreads();   // only barrier

    const float INF = __builtin_inff();
    float prev[P];
    #pragma unroll
    for (int c = 0; c < P; ++c) prev[c] = INF;
    float dg0 = INF;   // D[i-1][8j-1]; lane 0: stays INF forever

    // One DP step (row x vs my 8 cols), in-place:
    //   v[c] = cost_c + min3(prev[c](up), prev[c-1](diag), v[c-1](left))
    // INF identities make this also compute row 0's cumsum when prev==INF.
    auto STEP = [&](float left, float2 x) {
        float pm1 = prev[0];
        float v = fabsf(x.x - Y0[0]) + fabsf(x.y - Y1[0])
                + fminf(fminf(pm1, dg0), left);
        prev[0] = v;
        #pragma unroll
        for (int c = 1; c < P; ++c) {
            const float pc = prev[c];
            v = fabsf(x.x - Y0[c]) + fabsf(x.y - Y1[c])
              + fminf(fminf(pc, pm1), v);
            prev[c] = v;
            pm1 = pc;
        }
    };

    // ---- k = 0: lane 0 only, row 0, left = 0. dg0 NOT updated (stays INF).
    if (j == 0) STEP(0.0f, xs[0]);

    float2 xc;   // pipelined current-row register: xs[clamp(k - j)]
    {
        const int i1 = 1 - j;
        xc = xs[i1 > 0 ? i1 : 0];
    }

    // ---- Phase A: k = 1..63 (ramp; lane j activates at k == j) ----
    for (int k = 1; k < LANES; ++k) {
        const float left = dpp_wshr1_inf(prev[P - 1]);
        const int ip = k + 1 - j;
        const float2 xn = xs[ip > 0 ? ip : 0];   // prefetch next row
        if (k - j >= 0) STEP(left, xc);
        dg0 = left;                              // lane 0: left==INF here ✓
        xc = xn;
    }

    // ---- Phase B: k = 64..511 (steady state, all lanes active) ----
    #pragma unroll 4
    for (int k = LANES; k < NSEQ; ++k) {
        const float left = dpp_wshr1_inf(prev[P - 1]);
        const float2 xn = xs[k + 1 - j];         // prefetch (pad covers j=0,k=511)
        STEP(left, xc);
        dg0 = left;
        xc = xn;
    }

    // ---- Phase C: k = 512..574 (drain; lane j active while k - j < 512) ----
    for (int k = NSEQ; k < NSEQ + LANES - 1; ++k) {
        const float left = dpp_wshr1_inf(prev[P - 1]);
        const int ip = k + 1 - j;
        const float2 xn = xs[ip < NSEQ ? ip : NSEQ - 1];
        if (k - j < NSEQ) STEP(left, xc);
        dg0 = left;
        xc = xn;
    }

    if (j == LANES - 1) per_batch[b] = prev[P - 1];   // D[N-1][N-1]
}

__global__ void dtw_reduce(const float* __restrict__ per_batch,
                           float* __restrict__ out)
{
    float v = per_batch[threadIdx.x];
    #pragma unroll
    for (int off = 32; off >= 1; off >>= 1)
        v += __shfl_down(v, off);
    if (threadIdx.x == 0)
        out[0] = v * (1.0f / BATCH);
}

extern "C" void kernel_launch(void* const* d_in, const int* in_sizes, int n_in,
                              void* d_out, int out_size, void* d_ws, size_t ws_size,
                              hipStream_t stream) {
    const float* pred   = (const float*)d_in[0];
    const float* target = (const float*)d_in[1];
    float* out = (float*)d_out;
    float* per_batch = (float*)d_ws;

    dtw_strip<<<BATCH, LANES, 0, stream>>>(pred, target, per_batch);
    dtw_reduce<<<1, 64, 0, stream>>>(per_batch, out);
}